// Round 5
// baseline (229.112 us; speedup 1.0000x reference)
//
#include <hip/hip_runtime.h>
#include <hip/hip_bf16.h>
#include <math.h>

typedef unsigned short u16;
typedef __bf16 bf16x8 __attribute__((ext_vector_type(8)));
typedef float f32x4 __attribute__((ext_vector_type(4)));
typedef unsigned short u16x8 __attribute__((ext_vector_type(8)));

typedef const __attribute__((address_space(1))) void* gas_ptr;
typedef __attribute__((address_space(3))) void* las_ptr;

__device__ __forceinline__ float bf2f(u16 u) {
    union { unsigned int i; float f; } x;
    x.i = ((unsigned int)u) << 16;
    return x.f;
}
__device__ __forceinline__ u16 f2bf(float f) {
    __hip_bfloat16 h = __float2bfloat16(f);
    return __builtin_bit_cast(u16, h);
}
__device__ __forceinline__ __bf16 f2bfr(float f) {
    __hip_bfloat16 h = __float2bfloat16(f);
    return __builtin_bit_cast(__bf16, h);
}
__device__ __forceinline__ void load_lds16(const void* g, void* l) {
    __builtin_amdgcn_global_load_lds((gas_ptr)g, (las_ptr)l, 16, 0, 0);
}
__device__ __forceinline__ void phase_bar() {
    __builtin_amdgcn_sched_barrier(0);
    __builtin_amdgcn_s_barrier();
    __builtin_amdgcn_sched_barrier(0);
}
#define VMCNT4() asm volatile("s_waitcnt vmcnt(4)" ::: "memory")

// ---------------------------------------------------------------------------
// f32 -> bf16 conversion (weights). grid = n/1024 blocks.
// ---------------------------------------------------------------------------
__global__ __launch_bounds__(256) void cvt_k(const float* __restrict__ in,
                                             u16* __restrict__ outp) {
    const int i = blockIdx.x * 256 + threadIdx.x;
    const float4 v = ((const float4*)in)[i];
    ushort4 o;
    o.x = f2bf(v.x); o.y = f2bf(v.y); o.z = f2bf(v.z); o.w = f2bf(v.w);
    ((ushort4*)outp)[i] = o;
}

// ---------------------------------------------------------------------------
// LayerNorm: one block per row (C=512), 256 threads, 2 elems/thread.
// ---------------------------------------------------------------------------
__global__ __launch_bounds__(256) void ln_k(const float* __restrict__ inp,
                                            const float* __restrict__ gw,
                                            const float* __restrict__ gb,
                                            u16* __restrict__ outp) {
    const int row = blockIdx.x, t = threadIdx.x;
    const float2 v = ((const float2*)(inp + (size_t)row * 512))[t];
    float s = v.x + v.y, q = v.x * v.x + v.y * v.y;
    #pragma unroll
    for (int o = 1; o < 64; o <<= 1) {
        s += __shfl_xor(s, o);
        q += __shfl_xor(q, o);
    }
    __shared__ float rs[4], rq[4];
    const int w = t >> 6;
    if ((t & 63) == 0) { rs[w] = s; rq[w] = q; }
    __syncthreads();
    s = rs[0] + rs[1] + rs[2] + rs[3];
    q = rq[0] + rq[1] + rq[2] + rq[3];
    const float mean = s * (1.0f / 512.0f);
    const float var = q * (1.0f / 512.0f) - mean * mean;
    const float rstd = rsqrtf(var + 1e-5f);
    u16* op = outp + (size_t)row * 512;
    op[2 * t]     = f2bf((v.x - mean) * rstd * gw[2 * t]     + gb[2 * t]);
    op[2 * t + 1] = f2bf((v.y - mean) * rstd * gw[2 * t + 1] + gb[2 * t + 1]);
}

// ---------------------------------------------------------------------------
// 8-phase GEMM: C[m,n] = sum_k A[m,k]*W[n,k] (+epilogue).
// BM = M_REP*32 (256 or 128), BN = 256, BK = 64. 512 threads = 8 waves (2Mx4N),
// per-wave tile (BM/2)x64 via M_REP x 4 mfma 16x16x32 frags.
// LDS: 2 dbuf x (A BMx64 + B 256x64) bf16, XOR-swizzled granules (T2).
// Schedule (T3+T4): 2 K-tiles/iter, 8 phases, counted vmcnt(4) at p4/p8 only.
// vmcnt ledger (AL = BM/128 A-loads per thread per half-call):
//   prologue: 2AL+8 issued, vmcnt(4) keeps B(t1) only -> tile0 complete.
//   p4: outstanding 4+2AL+4, vmcnt(4) keeps B(Ta+2) -> buf1 complete for p5.
//   p8: symmetric -> buf0 complete for next p1.
// EPI 0: out bf16 = acc ; EPI 1: out f32 = acc+bias+res ; EPI 2: bf16 gelu.
// ---------------------------------------------------------------------------
template<int EPI, int M_REP>
__global__ __launch_bounds__(512, 2) void gemm8(const u16* __restrict__ A,
                                                const u16* __restrict__ W,
                                                const float* __restrict__ bias,
                                                const float* __restrict__ res_f,
                                                void* __restrict__ outp,
                                                int M, int N, int K) {
    constexpr int BM  = M_REP * 32;    // 256 or 128
    constexpr int IPQ = M_REP / 4;     // M-frags per quadrant: 2 or 1
    constexpr int AL  = BM / 128;      // gload_lds per A-half per thread: 2 or 1
    __shared__ __bf16 As[2][BM * 64];
    __shared__ __bf16 Bs[2][256 * 64];
    const int t = threadIdx.x;
    const int l = t & 63;
    const int wid = t >> 6;
    const int wm = wid >> 2, wn = wid & 3;
    const int bm = blockIdx.x * BM, bn = blockIdx.y * 256;
    const int r = l & 15, g4 = l >> 4;
    const int nk = K >> 6;
    const int kmask = nk - 1;          // nk is a power of 2 for all our shapes

    f32x4 acc[M_REP][4] = {};
    bf16x8 bfr[4][2];
    bf16x8 af[IPQ][2];

    auto stageA = [&](int buf, int h, int kt) __attribute__((always_inline)) {
        const int k0 = (kt & kmask) << 6;
        #pragma unroll
        for (int j = 0; j < AL; ++j) {
            const int gl = h * (BM * 4) + j * 512 + t;
            const int row = gl >> 3, gc = gl & 7;
            load_lds16(A + (size_t)(bm + row) * K + k0 + ((gc ^ (row & 7)) << 3),
                       &As[buf][gl << 3]);
        }
    };
    auto stageB = [&](int buf, int h, int kt) __attribute__((always_inline)) {
        const int k0 = (kt & kmask) << 6;
        #pragma unroll
        for (int j = 0; j < 2; ++j) {
            const int gl = h * 1024 + j * 512 + t;
            const int row = gl >> 3, gc = gl & 7;
            load_lds16(W + (size_t)(bn + row) * K + k0 + ((gc ^ (row & 7)) << 3),
                       &Bs[buf][gl << 3]);
        }
    };
    auto dsB = [&](int buf) __attribute__((always_inline)) {
        #pragma unroll
        for (int j = 0; j < 4; ++j) {
            #pragma unroll
            for (int ks = 0; ks < 2; ++ks) {
                const int row = wn * 64 + j * 16 + r;
                const int gc = ks * 4 + g4;
                bfr[j][ks] = *(const bf16x8*)&Bs[buf][((row << 3) | (gc ^ (row & 7))) << 3];
            }
        }
    };
    auto dsA = [&](int buf, int q) __attribute__((always_inline)) {
        #pragma unroll
        for (int ii = 0; ii < IPQ; ++ii) {
            #pragma unroll
            for (int ks = 0; ks < 2; ++ks) {
                const int row = wm * (BM / 2) + (q * IPQ + ii) * 16 + r;
                const int gc = ks * 4 + g4;
                af[ii][ks] = *(const bf16x8*)&As[buf][((row << 3) | (gc ^ (row & 7))) << 3];
            }
        }
    };
    auto mfmaQ = [&](int q) __attribute__((always_inline)) {
        __builtin_amdgcn_s_setprio(1);
        #pragma unroll
        for (int ii = 0; ii < IPQ; ++ii)
            #pragma unroll
            for (int j = 0; j < 4; ++j)
                #pragma unroll
                for (int ks = 0; ks < 2; ++ks)
                    acc[q * IPQ + ii][j] = __builtin_amdgcn_mfma_f32_16x16x32_bf16(
                        af[ii][ks], bfr[j][ks], acc[q * IPQ + ii][j], 0, 0, 0);
        __builtin_amdgcn_s_setprio(0);
    };

    // prologue: tile0 (A+B) -> buf0, tile1 B -> buf1
    stageA(0, 0, 0); stageA(0, 1, 0);
    stageB(0, 0, 0); stageB(0, 1, 0);
    stageB(1, 0, 1); stageB(1, 1, 1);
    VMCNT4();                      // retires all tile0 loads, keeps B(tile1)
    phase_bar();

    const int niter = nk >> 1;
    for (int it = 0; it < niter; ++it) {
        const int Ta = 2 * it;
        // p1: compute q0 of tile Ta (buf0); stage A(Ta+1)->buf1
        dsB(0); dsA(0, 0);
        stageA(1, 0, Ta + 1); stageA(1, 1, Ta + 1);
        phase_bar(); mfmaQ(0); phase_bar();
        // p2: buf0.B fully read at p1 -> stage B(Ta+2)->buf0
        dsA(0, 1); stageB(0, 0, Ta + 2);
        phase_bar(); mfmaQ(1); phase_bar();
        // p3
        dsA(0, 2); stageB(0, 1, Ta + 2);
        phase_bar(); mfmaQ(2); phase_bar();
        // p4: vmcnt(4) retires A(Ta+1)+B(Ta+1) => buf1 complete for p5
        dsA(0, 3); VMCNT4();
        phase_bar(); mfmaQ(3); phase_bar();
        // p5: compute q0 of tile Ta+1 (buf1); buf0.A read done at p4 -> stage A(Ta+2)
        dsB(1); dsA(1, 0); stageA(0, 0, Ta + 2);
        phase_bar(); mfmaQ(0); phase_bar();
        // p6
        dsA(1, 1); stageA(0, 1, Ta + 2);
        phase_bar(); mfmaQ(1); phase_bar();
        // p7: buf1.B fully read at p5 -> stage B(Ta+3)->buf1
        dsA(1, 2); stageB(1, 0, Ta + 3);
        phase_bar(); mfmaQ(2); phase_bar();
        // p8: vmcnt(4) retires A(Ta+2)+B(Ta+2) => buf0 complete for next p1
        dsA(1, 3); stageB(1, 1, Ta + 3); VMCNT4();
        phase_bar(); mfmaQ(3); phase_bar();
    }

    // epilogue
    #pragma unroll
    for (int i = 0; i < M_REP; ++i) {
        #pragma unroll
        for (int j = 0; j < 4; ++j) {
            #pragma unroll
            for (int rr = 0; rr < 4; ++rr) {
                const int m = bm + wm * (BM / 2) + i * 16 + g4 * 4 + rr;
                const int n = bn + wn * 64 + j * 16 + r;
                float v = acc[i][j][rr];
                const size_t idx = (size_t)m * N + n;
                if (EPI == 0) {
                    ((u16*)outp)[idx] = f2bf(v);
                } else if (EPI == 1) {
                    ((float*)outp)[idx] = v + bias[n] + res_f[idx];
                } else {
                    v += bias[n];
                    v = 0.5f * v * (1.0f + erff(v * 0.70710678118654752f));
                    ((u16*)outp)[idx] = f2bf(v);
                }
            }
        }
    }
}

// ---------------------------------------------------------------------------
// Fused attention per (window, head): S = QK^T + 0.1*rpe ; Mpart = sum|S| ;
// P' = 1 - cos(S/||S||row * pi/2) ; O' = P' @ V  (M factor applied later).
// ---------------------------------------------------------------------------
__global__ __launch_bounds__(256) void attn_k(const u16* __restrict__ qkv,
                                              const float* __restrict__ rpe,
                                              float* __restrict__ Mpart,
                                              u16* __restrict__ Obuf) {
    const int blk = blockIdx.x;
    const int wh = blk >> 3, head = blk & 7;
    const int himg = wh & 63;
    const int t = threadIdx.x, l = t & 63, w = t >> 6;
    __shared__ __bf16 Qs[4096];
    __shared__ __bf16 Ks[4096];
    __shared__ __bf16 Vt[4096];
    __shared__ __bf16 Ps[4096];
    __shared__ float red[4];

    #pragma unroll
    for (int p = 0; p < 2; ++p) {
        const int sb = (p * 256 + t) << 4;
        const int row = sb >> 7;
        const int gl = ((sb >> 4) & 7) ^ (row & 7);
        const size_t gsrc = (size_t)(wh * 64 + row) * 1536 + head * 64 + gl * 8;
        const int lbase = p * 2048 + w * 512;
        load_lds16(qkv + gsrc, &Qs[lbase]);
        load_lds16(qkv + gsrc + 512, &Ks[lbase]);
    }
    {
        const int k = t >> 2, dc = (t & 3) * 16;
        const u16* vr = qkv + (size_t)(wh * 64 + k) * 1536 + 1024 + head * 64 + dc;
        u16x8 v0 = *(const u16x8*)vr;
        u16x8 v1 = *(const u16x8*)(vr + 8);
        const int g = k >> 3, klo = k & 7;
        #pragma unroll
        for (int i = 0; i < 8; ++i) {
            const int d0 = dc + i, d1 = dc + 8 + i;
            Vt[d0 * 64 + ((g ^ (d0 & 7)) << 3) + klo] = __builtin_bit_cast(__bf16, (u16)v0[i]);
            Vt[d1 * 64 + ((g ^ (d1 & 7)) << 3) + klo] = __builtin_bit_cast(__bf16, (u16)v1[i]);
        }
    }
    __syncthreads();

    const int r = l & 15, g4 = l >> 4;
    f32x4 acc[4] = {};
    #pragma unroll
    for (int h = 0; h < 2; ++h) {
        const int rowq = w * 16 + r;
        bf16x8 aq = *(const bf16x8*)&Qs[rowq * 64 + (((h * 4 + g4) ^ (rowq & 7)) << 3)];
        #pragma unroll
        for (int j = 0; j < 4; ++j) {
            const int rowk = j * 16 + r;
            bf16x8 bk = *(const bf16x8*)&Ks[rowk * 64 + (((h * 4 + g4) ^ (rowk & 7)) << 3)];
            acc[j] = __builtin_amdgcn_mfma_f32_16x16x32_bf16(aq, bk, acc[j], 0, 0, 0);
        }
    }

    float v[4][4];
    float asum = 0.f;
    float ss[4] = {0.f, 0.f, 0.f, 0.f};
    const size_t rpe_base = (size_t)(himg * 8 + head) * 4096 + (size_t)(w * 16 + g4 * 4) * 64 + r;
    #pragma unroll
    for (int j = 0; j < 4; ++j) {
        #pragma unroll
        for (int rr = 0; rr < 4; ++rr) {
            const float val = acc[j][rr] + 0.1f * rpe[rpe_base + rr * 64 + j * 16];
            v[j][rr] = val;
            asum += fabsf(val);
            ss[rr] += val * val;
        }
    }
    #pragma unroll
    for (int m = 1; m < 16; m <<= 1) {
        #pragma unroll
        for (int rr = 0; rr < 4; ++rr) ss[rr] += __shfl_xor(ss[rr], m);
    }
    float srev[4];
    #pragma unroll
    for (int rr = 0; rr < 4; ++rr)
        srev[rr] = 0.25f / fmaxf(sqrtf(ss[rr]), 1e-12f);

    #pragma unroll
    for (int j = 0; j < 4; ++j) {
        #pragma unroll
        for (int rr = 0; rr < 4; ++rr) {
            const float pv = 1.0f - __builtin_amdgcn_cosf(v[j][rr] * srev[rr]);
            const int rl = g4 * 4 + rr;
            const int c = j * 16 + r;
            Ps[w * 1024 + rl * 64 + (((c >> 3) ^ (rl & 7)) << 3) + (c & 7)] = f2bfr(pv);
        }
    }

    f32x4 oacc[4] = {};
    #pragma unroll
    for (int ks = 0; ks < 2; ++ks) {
        const int ga = ks * 4 + g4;
        bf16x8 pa = *(const bf16x8*)&Ps[w * 1024 + r * 64 + ((ga ^ (r & 7)) << 3)];
        #pragma unroll
        for (int j = 0; j < 4; ++j) {
            const int d = j * 16 + r;
            bf16x8 vb = *(const bf16x8*)&Vt[d * 64 + ((ga ^ (d & 7)) << 3)];
            oacc[j] = __builtin_amdgcn_mfma_f32_16x16x32_bf16(pa, vb, oacc[j], 0, 0, 0);
        }
    }

    #pragma unroll
    for (int j = 0; j < 4; ++j) {
        #pragma unroll
        for (int rr = 0; rr < 4; ++rr) {
            const int token = wh * 64 + w * 16 + g4 * 4 + rr;
            Obuf[(size_t)token * 512 + head * 64 + j * 16 + r] = f2bf(oacc[j][rr]);
        }
    }

    #pragma unroll
    for (int o = 1; o < 64; o <<= 1) asum += __shfl_xor(asum, o);
    if (l == 0) red[w] = asum;
    __syncthreads();
    if (t == 0) Mpart[blk] = red[0] + red[1] + red[2] + red[3];
}

// ---------------------------------------------------------------------------
// M finalize: M_w = mean|S| per window; M = max(M_w / max_w, 0.5). 1 block.
// ---------------------------------------------------------------------------
__global__ __launch_bounds__(256) void mfinal_k(const float* __restrict__ Mpart,
                                                float* __restrict__ M) {
    const int t = threadIdx.x;
    float m = 0.f;
    #pragma unroll
    for (int h = 0; h < 8; ++h) m += Mpart[t * 8 + h];
    m *= (1.0f / 32768.0f);
    float mx = m;
    #pragma unroll
    for (int o = 1; o < 64; o <<= 1) mx = fmaxf(mx, __shfl_xor(mx, o));
    __shared__ float red[4];
    if ((t & 63) == 0) red[t >> 6] = mx;
    __syncthreads();
    mx = fmaxf(fmaxf(red[0], red[1]), fmaxf(red[2], red[3]));
    M[t] = fmaxf(m / mx, 0.5f);
}

// ---------------------------------------------------------------------------
// A1 = M*O' + (1-M)*x   (bf16 out). 8 elems/thread.
// ---------------------------------------------------------------------------
__global__ __launch_bounds__(256) void a1_k(const u16* __restrict__ O,
                                            const float* __restrict__ M,
                                            const float* __restrict__ x,
                                            u16* __restrict__ A1) {
    const size_t i8 = ((size_t)blockIdx.x * 256 + threadIdx.x) * 8;
    const float Mw = M[i8 >> 15];
    const float rf = 1.0f - Mw;
    const u16x8 ov = *(const u16x8*)(O + i8);
    const float4 x0 = *(const float4*)(x + i8);
    const float4 x1 = *(const float4*)(x + i8 + 4);
    u16x8 res;
    res[0] = f2bf(bf2f(ov[0]) * Mw + x0.x * rf);
    res[1] = f2bf(bf2f(ov[1]) * Mw + x0.y * rf);
    res[2] = f2bf(bf2f(ov[2]) * Mw + x0.z * rf);
    res[3] = f2bf(bf2f(ov[3]) * Mw + x0.w * rf);
    res[4] = f2bf(bf2f(ov[4]) * Mw + x1.x * rf);
    res[5] = f2bf(bf2f(ov[5]) * Mw + x1.y * rf);
    res[6] = f2bf(bf2f(ov[6]) * Mw + x1.z * rf);
    res[7] = f2bf(bf2f(ov[7]) * Mw + x1.w * rf);
    *(u16x8*)(A1 + i8) = res;
}

// ---------------------------------------------------------------------------
extern "C" void kernel_launch(void* const* d_in, const int* in_sizes, int n_in,
                              void* d_out, int out_size, void* d_ws, size_t ws_size,
                              hipStream_t stream) {
    (void)in_sizes; (void)n_in; (void)out_size; (void)ws_size;
    const float* x      = (const float*)d_in[0];
    const float* rpe    = (const float*)d_in[1];
    const float* qkv_w  = (const float*)d_in[2];
    const float* proj_w = (const float*)d_in[3];
    const float* proj_b = (const float*)d_in[4];
    const float* n1w    = (const float*)d_in[5];
    const float* n1b    = (const float*)d_in[6];
    const float* n2w    = (const float*)d_in[7];
    const float* n2b    = (const float*)d_in[8];
    const float* fc1w   = (const float*)d_in[9];
    const float* fc1b   = (const float*)d_in[10];
    const float* fc2w   = (const float*)d_in[11];
    const float* fc2b   = (const float*)d_in[12];
    float* out = (float*)d_out;

    char* ws = (char*)d_ws;
    float* Mpart = (float*)ws;                         // 8 KB
    float* Mbuf  = (float*)(ws + 8192);                // 1 KB
    u16* wqkv  = (u16*)(ws + 16384);                   // 1,572,864 B
    u16* wproj = (u16*)(ws + 16384 + 1572864);         // 524,288 B
    u16* wfc1  = (u16*)(ws + 16384 + 2097152);         // 2,097,152 B
    u16* wfc2  = (u16*)(ws + 16384 + 4194304);         // 2,097,152 B
    u16* bufA  = (u16*)(ws + 6307840);                 // 16,777,216 B (img/A1/h1)
    char* R    = ws + 23085056;                        // overlay region
    u16*   qkvb = (u16*)R;                             // 50,331,648 B
    u16*   Obuf = (u16*)(R + 50331648);                // 16,777,216 B
    u16*   gbuf = (u16*)R;                             // 67,108,864 B (qkv+O dead)

    // 0. weight conversions f32->bf16
    cvt_k<<<768, 256, 0, stream>>>(qkv_w, wqkv);
    cvt_k<<<256, 256, 0, stream>>>(proj_w, wproj);
    cvt_k<<<1024, 256, 0, stream>>>(fc1w, wfc1);
    cvt_k<<<1024, 256, 0, stream>>>(fc2w, wfc2);
    // 1. LN1: x -> img (bufA, bf16)
    ln_k<<<16384, 256, 0, stream>>>(x, n1w, n1b, bufA);
    // 2. qkv = img @ qkv_w^T  (qkvb bf16)
    gemm8<0, 8><<<dim3(64, 6), 512, 0, stream>>>(bufA, wqkv, nullptr, nullptr,
                                                 qkvb, 16384, 1536, 512);
    // 3. fused attention: O' (no M factor) + Mpart
    attn_k<<<2048, 256, 0, stream>>>(qkvb, rpe, Mpart, Obuf);
    // 4. M finalize
    mfinal_k<<<1, 256, 0, stream>>>(Mpart, Mbuf);
    // 5. A1 = M*O' + (1-M)*x  (bufA bf16)
    a1_k<<<4096, 256, 0, stream>>>(Obuf, Mbuf, x, bufA);
    // 6. x1 = x + A1 @ proj_w^T + proj_b  -> d_out (f32)
    gemm8<1, 4><<<dim3(128, 2), 512, 0, stream>>>(bufA, wproj, proj_b, x,
                                                  out, 16384, 512, 512);
    // 7. LN2: x1 -> h1 (bufA bf16)
    ln_k<<<16384, 256, 0, stream>>>(out, n2w, n2b, bufA);
    // 8. g = gelu(h1 @ fc1_w^T + fc1_b)  (gbuf bf16)
    gemm8<2, 8><<<dim3(64, 8), 512, 0, stream>>>(bufA, wfc1, fc1b, nullptr,
                                                 gbuf, 16384, 2048, 512);
    // 9. out = x1 + g @ fc2_w^T + fc2_b  (f32, in-place read of x1)
    gemm8<1, 4><<<dim3(128, 2), 512, 0, stream>>>(gbuf, wfc2, fc2b, out,
                                                  out, 16384, 512, 2048);
}

// Round 6
// 213.560 us; speedup vs baseline: 1.0728x; 1.0728x over previous
//
#include <hip/hip_runtime.h>
#include <hip/hip_bf16.h>
#include <math.h>

typedef unsigned short u16;
typedef __bf16 bf16x8 __attribute__((ext_vector_type(8)));
typedef float f32x4 __attribute__((ext_vector_type(4)));
typedef unsigned short u16x8 __attribute__((ext_vector_type(8)));

typedef const __attribute__((address_space(1))) void* gas_ptr;
typedef __attribute__((address_space(3))) void* las_ptr;

__device__ __forceinline__ float bf2f(u16 u) {
    union { unsigned int i; float f; } x;
    x.i = ((unsigned int)u) << 16;
    return x.f;
}
__device__ __forceinline__ u16 f2bf(float f) {
    __hip_bfloat16 h = __float2bfloat16(f);
    return __builtin_bit_cast(u16, h);
}
__device__ __forceinline__ __bf16 f2bfr(float f) {
    __hip_bfloat16 h = __float2bfloat16(f);
    return __builtin_bit_cast(__bf16, h);
}
__device__ __forceinline__ void load_lds16(const void* g, void* l) {
    __builtin_amdgcn_global_load_lds((gas_ptr)g, (las_ptr)l, 16, 0, 0);
}

// ---------------------------------------------------------------------------
// f32 -> bf16 conversion (weights). grid = n/1024 blocks.
// ---------------------------------------------------------------------------
__global__ __launch_bounds__(256) void cvt_k(const float* __restrict__ in,
                                             u16* __restrict__ outp) {
    const int i = blockIdx.x * 256 + threadIdx.x;
    const float4 v = ((const float4*)in)[i];
    ushort4 o;
    o.x = f2bf(v.x); o.y = f2bf(v.y); o.z = f2bf(v.z); o.w = f2bf(v.w);
    ((ushort4*)outp)[i] = o;
}

// ---------------------------------------------------------------------------
// LayerNorm: one block per row (C=512), 256 threads, 2 elems/thread.
// BF16IN=false: f32 input; true: bf16 input. Output bf16.
// ---------------------------------------------------------------------------
template<bool BF16IN>
__global__ __launch_bounds__(256) void ln_k(const void* __restrict__ inp,
                                            const float* __restrict__ gw,
                                            const float* __restrict__ gb,
                                            u16* __restrict__ outp) {
    const int row = blockIdx.x, t = threadIdx.x;
    float v0, v1;
    if (BF16IN) {
        const u16* rp = (const u16*)inp + (size_t)row * 512;
        v0 = bf2f(rp[2 * t]); v1 = bf2f(rp[2 * t + 1]);
    } else {
        const float2 v = ((const float2*)((const float*)inp + (size_t)row * 512))[t];
        v0 = v.x; v1 = v.y;
    }
    float s = v0 + v1, q = v0 * v0 + v1 * v1;
    #pragma unroll
    for (int o = 1; o < 64; o <<= 1) {
        s += __shfl_xor(s, o);
        q += __shfl_xor(q, o);
    }
    __shared__ float rs[4], rq[4];
    const int w = t >> 6;
    if ((t & 63) == 0) { rs[w] = s; rq[w] = q; }
    __syncthreads();
    s = rs[0] + rs[1] + rs[2] + rs[3];
    q = rq[0] + rq[1] + rq[2] + rq[3];
    const float mean = s * (1.0f / 512.0f);
    const float var = q * (1.0f / 512.0f) - mean * mean;
    const float rstd = rsqrtf(var + 1e-5f);
    u16* op = outp + (size_t)row * 512;
    op[2 * t]     = f2bf((v0 - mean) * rstd * gw[2 * t]     + gb[2 * t]);
    op[2 * t + 1] = f2bf((v1 - mean) * rstd * gw[2 * t + 1] + gb[2 * t + 1]);
}

// ---------------------------------------------------------------------------
// GEMM C[m,n] = sum_k A[m,k]*W[n,k] (+epilogue). 128x128 tile, BK=32,
// 4 waves (2x2), each wave 64x64 via 4x4 mfma 16x16x32.
// AFUSE: A-tile is computed on the fly as a1 = M*O' + (1-M)*x (reg-staged
//        ds_write into the same swizzled LDS slots); A ptr unused.
// EPI 0: out bf16 = acc                          (qkv)
// EPI 1: out bf16 = acc + bias + res_f32         (proj -> x1 bf16)
// EPI 2: out bf16 = gelu(acc + bias)             (fc1)
// EPI 3: out f32  = acc + bias + bf16(res_bf)    (fc2 -> final)
// ---------------------------------------------------------------------------
template<int EPI, bool AFUSE>
__global__ __launch_bounds__(256) void gemm_bt(const u16* __restrict__ A,
                                               const u16* __restrict__ W,
                                               const float* __restrict__ bias,
                                               const float* __restrict__ res_f,
                                               const u16* __restrict__ res_bf,
                                               void* __restrict__ outp,
                                               int M, int N, int K,
                                               const float* __restrict__ aM,
                                               const u16* __restrict__ aO,
                                               const float* __restrict__ aX) {
    __shared__ __bf16 As[2][128 * 32];
    __shared__ __bf16 Bs[2][128 * 32];
    const int t = threadIdx.x;
    const int l = t & 63;
    const int w = t >> 6;
    const int wm = w & 1, wn = w >> 1;
    const int bm = blockIdx.x * 128, bn = blockIdx.y * 128;

    f32x4 acc[4][4] = {};

    auto stage = [&](int buf, int kt) {
        #pragma unroll
        for (int p = 0; p < 2; ++p) {
            const int slot = p * 256 + t;            // 16B granule index
            const int row = slot >> 2;               // 4 granules per row (BK=32)
            const int gl = (slot & 3) ^ (row & 3);   // swizzled src col-group
            if (AFUSE) {
                const int grow = bm + row;
                const size_t gidx = (size_t)grow * K + kt + gl * 8;
                const float Mw = aM[grow >> 6];
                const float rf = 1.0f - Mw;
                const u16x8 ov = *(const u16x8*)(aO + gidx);
                const float4 x0 = *(const float4*)(aX + gidx);
                const float4 x1 = *(const float4*)(aX + gidx + 4);
                bf16x8 val;
                val[0] = f2bfr(Mw * bf2f(ov[0]) + rf * x0.x);
                val[1] = f2bfr(Mw * bf2f(ov[1]) + rf * x0.y);
                val[2] = f2bfr(Mw * bf2f(ov[2]) + rf * x0.z);
                val[3] = f2bfr(Mw * bf2f(ov[3]) + rf * x0.w);
                val[4] = f2bfr(Mw * bf2f(ov[4]) + rf * x1.x);
                val[5] = f2bfr(Mw * bf2f(ov[5]) + rf * x1.y);
                val[6] = f2bfr(Mw * bf2f(ov[6]) + rf * x1.z);
                val[7] = f2bfr(Mw * bf2f(ov[7]) + rf * x1.w);
                *(bf16x8*)&As[buf][slot * 8] = val;
            } else {
                load_lds16(A + (size_t)(bm + row) * K + kt + gl * 8,
                           &As[buf][p * 2048 + w * 512]);
            }
            load_lds16(W + (size_t)(bn + row) * K + kt + gl * 8,
                       &Bs[buf][p * 2048 + w * 512]);
        }
    };

    const int nk = K >> 5;
    stage(0, 0);
    __syncthreads();
    for (int s = 0; s < nk; ++s) {
        if (s + 1 < nk) stage((s + 1) & 1, (s + 1) << 5);
        const int buf = s & 1;
        const int r = l & 15, g = l >> 4;
        bf16x8 af[4], bfr[4];
        #pragma unroll
        for (int i = 0; i < 4; ++i) {
            const int ra = wm * 64 + i * 16 + r;
            af[i] = *(const bf16x8*)&As[buf][ra * 32 + ((g ^ (ra & 3)) << 3)];
            const int rb = wn * 64 + i * 16 + r;
            bfr[i] = *(const bf16x8*)&Bs[buf][rb * 32 + ((g ^ (rb & 3)) << 3)];
        }
        #pragma unroll
        for (int i = 0; i < 4; ++i)
            #pragma unroll
            for (int j = 0; j < 4; ++j)
                acc[i][j] = __builtin_amdgcn_mfma_f32_16x16x32_bf16(af[i], bfr[j], acc[i][j], 0, 0, 0);
        __syncthreads();
    }

    #pragma unroll
    for (int i = 0; i < 4; ++i) {
        #pragma unroll
        for (int j = 0; j < 4; ++j) {
            #pragma unroll
            for (int rr = 0; rr < 4; ++rr) {
                const int m = bm + wm * 64 + i * 16 + ((l >> 4) << 2) + rr;
                const int n = bn + wn * 64 + j * 16 + (l & 15);
                float v = acc[i][j][rr];
                const size_t idx = (size_t)m * N + n;
                if (EPI == 0) {
                    ((u16*)outp)[idx] = f2bf(v);
                } else if (EPI == 1) {
                    ((u16*)outp)[idx] = f2bf(v + bias[n] + res_f[idx]);
                } else if (EPI == 2) {
                    v += bias[n];
                    v = 0.5f * v * (1.0f + erff(v * 0.70710678118654752f));
                    ((u16*)outp)[idx] = f2bf(v);
                } else {
                    ((float*)outp)[idx] = v + bias[n] + bf2f(res_bf[idx]);
                }
            }
        }
    }
}

// ---------------------------------------------------------------------------
// Fused attention per (window, head): S = QK^T + 0.1*rpe ; Mpart = sum|S| ;
// P' = 1 - cos(S/||S||row * pi/2) ; O' = P' @ V  (M factor applied later).
// ---------------------------------------------------------------------------
__global__ __launch_bounds__(256) void attn_k(const u16* __restrict__ qkv,
                                              const float* __restrict__ rpe,
                                              float* __restrict__ Mpart,
                                              u16* __restrict__ Obuf) {
    const int blk = blockIdx.x;
    const int wh = blk >> 3, head = blk & 7;
    const int himg = wh & 63;
    const int t = threadIdx.x, l = t & 63, w = t >> 6;
    __shared__ __bf16 Qs[4096];
    __shared__ __bf16 Ks[4096];
    __shared__ __bf16 Vt[4096];
    __shared__ __bf16 Ps[4096];
    __shared__ float red[4];

    #pragma unroll
    for (int p = 0; p < 2; ++p) {
        const int sb = (p * 256 + t) << 4;
        const int row = sb >> 7;
        const int gl = ((sb >> 4) & 7) ^ (row & 7);
        const size_t gsrc = (size_t)(wh * 64 + row) * 1536 + head * 64 + gl * 8;
        const int lbase = p * 2048 + w * 512;
        load_lds16(qkv + gsrc, &Qs[lbase]);
        load_lds16(qkv + gsrc + 512, &Ks[lbase]);
    }
    {
        const int k = t >> 2, dc = (t & 3) * 16;
        const u16* vr = qkv + (size_t)(wh * 64 + k) * 1536 + 1024 + head * 64 + dc;
        u16x8 v0 = *(const u16x8*)vr;
        u16x8 v1 = *(const u16x8*)(vr + 8);
        const int g = k >> 3, klo = k & 7;
        #pragma unroll
        for (int i = 0; i < 8; ++i) {
            const int d0 = dc + i, d1 = dc + 8 + i;
            Vt[d0 * 64 + ((g ^ (d0 & 7)) << 3) + klo] = __builtin_bit_cast(__bf16, (u16)v0[i]);
            Vt[d1 * 64 + ((g ^ (d1 & 7)) << 3) + klo] = __builtin_bit_cast(__bf16, (u16)v1[i]);
        }
    }
    __syncthreads();

    const int r = l & 15, g4 = l >> 4;
    f32x4 acc[4] = {};
    #pragma unroll
    for (int h = 0; h < 2; ++h) {
        const int rowq = w * 16 + r;
        bf16x8 aq = *(const bf16x8*)&Qs[rowq * 64 + (((h * 4 + g4) ^ (rowq & 7)) << 3)];
        #pragma unroll
        for (int j = 0; j < 4; ++j) {
            const int rowk = j * 16 + r;
            bf16x8 bk = *(const bf16x8*)&Ks[rowk * 64 + (((h * 4 + g4) ^ (rowk & 7)) << 3)];
            acc[j] = __builtin_amdgcn_mfma_f32_16x16x32_bf16(aq, bk, acc[j], 0, 0, 0);
        }
    }

    float v[4][4];
    float asum = 0.f;
    float ss[4] = {0.f, 0.f, 0.f, 0.f};
    const size_t rpe_base = (size_t)(himg * 8 + head) * 4096 + (size_t)(w * 16 + g4 * 4) * 64 + r;
    #pragma unroll
    for (int j = 0; j < 4; ++j) {
        #pragma unroll
        for (int rr = 0; rr < 4; ++rr) {
            const float val = acc[j][rr] + 0.1f * rpe[rpe_base + rr * 64 + j * 16];
            v[j][rr] = val;
            asum += fabsf(val);
            ss[rr] += val * val;
        }
    }
    #pragma unroll
    for (int m = 1; m < 16; m <<= 1) {
        #pragma unroll
        for (int rr = 0; rr < 4; ++rr) ss[rr] += __shfl_xor(ss[rr], m);
    }
    float srev[4];
    #pragma unroll
    for (int rr = 0; rr < 4; ++rr)
        srev[rr] = 0.25f / fmaxf(sqrtf(ss[rr]), 1e-12f);

    #pragma unroll
    for (int j = 0; j < 4; ++j) {
        #pragma unroll
        for (int rr = 0; rr < 4; ++rr) {
            const float pv = 1.0f - __builtin_amdgcn_cosf(v[j][rr] * srev[rr]);
            const int rl = g4 * 4 + rr;
            const int c = j * 16 + r;
            Ps[w * 1024 + rl * 64 + (((c >> 3) ^ (rl & 7)) << 3) + (c & 7)] = f2bfr(pv);
        }
    }

    f32x4 oacc[4] = {};
    #pragma unroll
    for (int ks = 0; ks < 2; ++ks) {
        const int ga = ks * 4 + g4;
        bf16x8 pa = *(const bf16x8*)&Ps[w * 1024 + r * 64 + ((ga ^ (r & 7)) << 3)];
        #pragma unroll
        for (int j = 0; j < 4; ++j) {
            const int d = j * 16 + r;
            bf16x8 vb = *(const bf16x8*)&Vt[d * 64 + ((ga ^ (d & 7)) << 3)];
            oacc[j] = __builtin_amdgcn_mfma_f32_16x16x32_bf16(pa, vb, oacc[j], 0, 0, 0);
        }
    }

    #pragma unroll
    for (int j = 0; j < 4; ++j) {
        #pragma unroll
        for (int rr = 0; rr < 4; ++rr) {
            const int token = wh * 64 + w * 16 + g4 * 4 + rr;
            Obuf[(size_t)token * 512 + head * 64 + j * 16 + r] = f2bf(oacc[j][rr]);
        }
    }

    #pragma unroll
    for (int o = 1; o < 64; o <<= 1) asum += __shfl_xor(asum, o);
    if (l == 0) red[w] = asum;
    __syncthreads();
    if (t == 0) Mpart[blk] = red[0] + red[1] + red[2] + red[3];
}

// ---------------------------------------------------------------------------
// M finalize: M_w = mean|S| per window; M = max(M_w / max_w, 0.5). 1 block.
// ---------------------------------------------------------------------------
__global__ __launch_bounds__(256) void mfinal_k(const float* __restrict__ Mpart,
                                                float* __restrict__ M) {
    const int t = threadIdx.x;
    float m = 0.f;
    #pragma unroll
    for (int h = 0; h < 8; ++h) m += Mpart[t * 8 + h];
    m *= (1.0f / 32768.0f);
    float mx = m;
    #pragma unroll
    for (int o = 1; o < 64; o <<= 1) mx = fmaxf(mx, __shfl_xor(mx, o));
    __shared__ float red[4];
    if ((t & 63) == 0) red[t >> 6] = mx;
    __syncthreads();
    mx = fmaxf(fmaxf(red[0], red[1]), fmaxf(red[2], red[3]));
    M[t] = fmaxf(m / mx, 0.5f);
}

// ---------------------------------------------------------------------------
extern "C" void kernel_launch(void* const* d_in, const int* in_sizes, int n_in,
                              void* d_out, int out_size, void* d_ws, size_t ws_size,
                              hipStream_t stream) {
    (void)in_sizes; (void)n_in; (void)out_size; (void)ws_size;
    const float* x      = (const float*)d_in[0];
    const float* rpe    = (const float*)d_in[1];
    const float* qkv_w  = (const float*)d_in[2];
    const float* proj_w = (const float*)d_in[3];
    const float* proj_b = (const float*)d_in[4];
    const float* n1w    = (const float*)d_in[5];
    const float* n1b    = (const float*)d_in[6];
    const float* n2w    = (const float*)d_in[7];
    const float* n2b    = (const float*)d_in[8];
    const float* fc1w   = (const float*)d_in[9];
    const float* fc1b   = (const float*)d_in[10];
    const float* fc2w   = (const float*)d_in[11];
    const float* fc2b   = (const float*)d_in[12];
    float* out = (float*)d_out;

    char* ws = (char*)d_ws;
    float* Mpart = (float*)ws;                         // 8 KB
    float* Mbuf  = (float*)(ws + 8192);                // 1 KB
    u16* wqkv  = (u16*)(ws + 16384);                   // 1,572,864 B
    u16* wproj = (u16*)(ws + 16384 + 1572864);         // 524,288 B
    u16* wfc1  = (u16*)(ws + 16384 + 2097152);         // 2,097,152 B
    u16* wfc2  = (u16*)(ws + 16384 + 4194304);         // 2,097,152 B
    u16* bufA  = (u16*)(ws + 6307840);                 // 16.78 MB: img, then x1 (bf16)
    u16* bufB  = (u16*)(ws + 23085056);                // 16.78 MB: h1
    char* R    = ws + 39862272;                        // overlay region (67.1 MB)
    u16*   qkvb = (u16*)R;                             // 50,331,648 B
    u16*   Obuf = (u16*)(R + 50331648);                // 16,777,216 B
    u16*   gbuf = (u16*)R;                             // 67,108,864 B (qkv+O dead)

    // 0. weight conversions f32->bf16
    cvt_k<<<768, 256, 0, stream>>>(qkv_w, wqkv);
    cvt_k<<<256, 256, 0, stream>>>(proj_w, wproj);
    cvt_k<<<1024, 256, 0, stream>>>(fc1w, wfc1);
    cvt_k<<<1024, 256, 0, stream>>>(fc2w, wfc2);
    // 1. LN1: x -> img (bufA, bf16)
    ln_k<false><<<16384, 256, 0, stream>>>(x, n1w, n1b, bufA);
    // 2. qkv = img @ qkv_w^T  (qkvb bf16)
    gemm_bt<0, false><<<dim3(128, 12), 256, 0, stream>>>(
        bufA, wqkv, nullptr, nullptr, nullptr, qkvb, 16384, 1536, 512,
        nullptr, nullptr, nullptr);
    // 3. fused attention: O' (no M factor) + Mpart
    attn_k<<<2048, 256, 0, stream>>>(qkvb, rpe, Mpart, Obuf);
    // 4. M finalize
    mfinal_k<<<1, 256, 0, stream>>>(Mpart, Mbuf);
    // 5. x1 = x + a1 @ proj_w^T + proj_b -> bufA (bf16); a1 fused in staging
    gemm_bt<1, true><<<dim3(128, 4), 256, 0, stream>>>(
        nullptr, wproj, proj_b, x, nullptr, bufA, 16384, 512, 512,
        Mbuf, Obuf, x);
    // 6. LN2: x1 (bf16) -> h1 (bufB bf16)
    ln_k<true><<<16384, 256, 0, stream>>>(bufA, n2w, n2b, bufB);
    // 7. g = gelu(h1 @ fc1_w^T + fc1_b)  (gbuf bf16)
    gemm_bt<2, false><<<dim3(128, 16), 256, 0, stream>>>(
        bufB, wfc1, fc1b, nullptr, nullptr, gbuf, 16384, 2048, 512,
        nullptr, nullptr, nullptr);
    // 8. out = x1 + g @ fc2_w^T + fc2_b  (f32)
    gemm_bt<3, false><<<dim3(128, 4), 256, 0, stream>>>(
        gbuf, wfc2, fc2b, nullptr, bufA, out, 16384, 512, 2048,
        nullptr, nullptr, nullptr);
}

// Round 7
// 207.447 us; speedup vs baseline: 1.1044x; 1.0295x over previous
//
#include <hip/hip_runtime.h>
#include <hip/hip_bf16.h>
#include <math.h>

typedef unsigned short u16;
typedef __bf16 bf16x8 __attribute__((ext_vector_type(8)));
typedef float f32x4 __attribute__((ext_vector_type(4)));
typedef unsigned short u16x8 __attribute__((ext_vector_type(8)));

typedef const __attribute__((address_space(1))) void* gas_ptr;
typedef __attribute__((address_space(3))) void* las_ptr;

__device__ __forceinline__ float bf2f(u16 u) {
    union { unsigned int i; float f; } x;
    x.i = ((unsigned int)u) << 16;
    return x.f;
}
__device__ __forceinline__ u16 f2bf(float f) {
    __hip_bfloat16 h = __float2bfloat16(f);
    return __builtin_bit_cast(u16, h);
}
__device__ __forceinline__ __bf16 f2bfr(float f) {
    __hip_bfloat16 h = __float2bfloat16(f);
    return __builtin_bit_cast(__bf16, h);
}
__device__ __forceinline__ void load_lds16(const void* g, void* l) {
    __builtin_amdgcn_global_load_lds((gas_ptr)g, (las_ptr)l, 16, 0, 0);
}

// ---------------------------------------------------------------------------
// All 4 weight conversions f32->bf16 in one launch. 1024 elems/block.
// qkv: 768 blocks, proj: 256, fc1: 1024, fc2: 1024  (total 3072).
// ---------------------------------------------------------------------------
__global__ __launch_bounds__(256) void cvt_all_k(const float* __restrict__ qkv_w,
                                                 const float* __restrict__ proj_w,
                                                 const float* __restrict__ fc1w,
                                                 const float* __restrict__ fc2w,
                                                 u16* __restrict__ wqkv,
                                                 u16* __restrict__ wproj,
                                                 u16* __restrict__ wfc1,
                                                 u16* __restrict__ wfc2) {
    const int b = blockIdx.x;
    const float* src; u16* dst; int off;
    if (b < 768)       { src = qkv_w;  dst = wqkv;  off = b; }
    else if (b < 1024) { src = proj_w; dst = wproj; off = b - 768; }
    else if (b < 2048) { src = fc1w;   dst = wfc1;  off = b - 1024; }
    else               { src = fc2w;   dst = wfc2;  off = b - 2048; }
    const int i = off * 256 + threadIdx.x;
    const float4 v = ((const float4*)src)[i];
    ushort4 o;
    o.x = f2bf(v.x); o.y = f2bf(v.y); o.z = f2bf(v.z); o.w = f2bf(v.w);
    ((ushort4*)dst)[i] = o;
}

// ---------------------------------------------------------------------------
// LayerNorm: one block per row (C=512), 256 threads, 2 elems/thread.
// BF16IN=false: f32 input; true: bf16 input. Output bf16.
// ---------------------------------------------------------------------------
template<bool BF16IN>
__global__ __launch_bounds__(256) void ln_k(const void* __restrict__ inp,
                                            const float* __restrict__ gw,
                                            const float* __restrict__ gb,
                                            u16* __restrict__ outp) {
    const int row = blockIdx.x, t = threadIdx.x;
    float v0, v1;
    if (BF16IN) {
        const u16* rp = (const u16*)inp + (size_t)row * 512;
        v0 = bf2f(rp[2 * t]); v1 = bf2f(rp[2 * t + 1]);
    } else {
        const float2 v = ((const float2*)((const float*)inp + (size_t)row * 512))[t];
        v0 = v.x; v1 = v.y;
    }
    float s = v0 + v1, q = v0 * v0 + v1 * v1;
    #pragma unroll
    for (int o = 1; o < 64; o <<= 1) {
        s += __shfl_xor(s, o);
        q += __shfl_xor(q, o);
    }
    __shared__ float rs[4], rq[4];
    const int w = t >> 6;
    if ((t & 63) == 0) { rs[w] = s; rq[w] = q; }
    __syncthreads();
    s = rs[0] + rs[1] + rs[2] + rs[3];
    q = rq[0] + rq[1] + rq[2] + rq[3];
    const float mean = s * (1.0f / 512.0f);
    const float var = q * (1.0f / 512.0f) - mean * mean;
    const float rstd = rsqrtf(var + 1e-5f);
    u16* op = outp + (size_t)row * 512;
    op[2 * t]     = f2bf((v0 - mean) * rstd * gw[2 * t]     + gb[2 * t]);
    op[2 * t + 1] = f2bf((v1 - mean) * rstd * gw[2 * t + 1] + gb[2 * t + 1]);
}

// ---------------------------------------------------------------------------
// GEMM C[m,n] = sum_k A[m,k]*W[n,k] (+epilogue). 128x128 tile, BK=32,
// 4 waves (2x2), each wave 64x64 via 4x4 mfma 16x16x32.
// LDS swizzle: granule_in_row = data_granule ^ ((row>>1)&3). The frag-read's
// 16-lane service group (fixed g, rows r=0..15) then hits 8 distinct bank
// quads for r=0..7 (2-way repeat r=8..15, free) -> conflict-free ds_read_b128.
// AFUSE: A-tile computed on the fly as a1 = M*O' + (1-M)*x (reg-staged
//        ds_write into the same swizzled LDS slots); A ptr unused.
// EPI 0: out bf16 = acc                          (qkv)
// EPI 1: out bf16 = acc + bias + res_f32         (proj -> x1 bf16)
// EPI 2: out bf16 = gelu(acc + bias)             (fc1)
// EPI 3: out f32  = acc + bias + bf16(res_bf)    (fc2 -> final)
// ---------------------------------------------------------------------------
template<int EPI, bool AFUSE>
__global__ __launch_bounds__(256) void gemm_bt(const u16* __restrict__ A,
                                               const u16* __restrict__ W,
                                               const float* __restrict__ bias,
                                               const float* __restrict__ res_f,
                                               const u16* __restrict__ res_bf,
                                               void* __restrict__ outp,
                                               int M, int N, int K,
                                               const float* __restrict__ aM,
                                               const u16* __restrict__ aO,
                                               const float* __restrict__ aX) {
    __shared__ __bf16 As[2][128 * 32];
    __shared__ __bf16 Bs[2][128 * 32];
    const int t = threadIdx.x;
    const int l = t & 63;
    const int w = t >> 6;
    const int wm = w & 1, wn = w >> 1;
    const int bm = blockIdx.x * 128, bn = blockIdx.y * 128;

    f32x4 acc[4][4] = {};

    auto stage = [&](int buf, int kt) {
        #pragma unroll
        for (int p = 0; p < 2; ++p) {
            const int slot = p * 256 + t;                 // 16B granule index
            const int row = slot >> 2;                    // 4 granules per row
            const int gl = (slot & 3) ^ ((row >> 1) & 3); // swizzled src group
            if (AFUSE) {
                const int grow = bm + row;
                const size_t gidx = (size_t)grow * K + kt + gl * 8;
                const float Mw = aM[grow >> 6];
                const float rf = 1.0f - Mw;
                const u16x8 ov = *(const u16x8*)(aO + gidx);
                const float4 x0 = *(const float4*)(aX + gidx);
                const float4 x1 = *(const float4*)(aX + gidx + 4);
                bf16x8 val;
                val[0] = f2bfr(Mw * bf2f(ov[0]) + rf * x0.x);
                val[1] = f2bfr(Mw * bf2f(ov[1]) + rf * x0.y);
                val[2] = f2bfr(Mw * bf2f(ov[2]) + rf * x0.z);
                val[3] = f2bfr(Mw * bf2f(ov[3]) + rf * x0.w);
                val[4] = f2bfr(Mw * bf2f(ov[4]) + rf * x1.x);
                val[5] = f2bfr(Mw * bf2f(ov[5]) + rf * x1.y);
                val[6] = f2bfr(Mw * bf2f(ov[6]) + rf * x1.z);
                val[7] = f2bfr(Mw * bf2f(ov[7]) + rf * x1.w);
                *(bf16x8*)&As[buf][slot * 8] = val;
            } else {
                load_lds16(A + (size_t)(bm + row) * K + kt + gl * 8,
                           &As[buf][p * 2048 + w * 512]);
            }
            load_lds16(W + (size_t)(bn + row) * K + kt + gl * 8,
                       &Bs[buf][p * 2048 + w * 512]);
        }
    };

    const int nk = K >> 5;
    stage(0, 0);
    __syncthreads();
    for (int s = 0; s < nk; ++s) {
        if (s + 1 < nk) stage((s + 1) & 1, (s + 1) << 5);
        const int buf = s & 1;
        const int r = l & 15, g = l >> 4;
        bf16x8 af[4], bfr[4];
        #pragma unroll
        for (int i = 0; i < 4; ++i) {
            const int ra = wm * 64 + i * 16 + r;
            af[i] = *(const bf16x8*)&As[buf][ra * 32 + ((g ^ ((ra >> 1) & 3)) << 3)];
            const int rb = wn * 64 + i * 16 + r;
            bfr[i] = *(const bf16x8*)&Bs[buf][rb * 32 + ((g ^ ((rb >> 1) & 3)) << 3)];
        }
        #pragma unroll
        for (int i = 0; i < 4; ++i)
            #pragma unroll
            for (int j = 0; j < 4; ++j)
                acc[i][j] = __builtin_amdgcn_mfma_f32_16x16x32_bf16(af[i], bfr[j], acc[i][j], 0, 0, 0);
        __syncthreads();
    }

    #pragma unroll
    for (int i = 0; i < 4; ++i) {
        #pragma unroll
        for (int j = 0; j < 4; ++j) {
            #pragma unroll
            for (int rr = 0; rr < 4; ++rr) {
                const int m = bm + wm * 64 + i * 16 + ((l >> 4) << 2) + rr;
                const int n = bn + wn * 64 + j * 16 + (l & 15);
                float v = acc[i][j][rr];
                const size_t idx = (size_t)m * N + n;
                if (EPI == 0) {
                    ((u16*)outp)[idx] = f2bf(v);
                } else if (EPI == 1) {
                    ((u16*)outp)[idx] = f2bf(v + bias[n] + res_f[idx]);
                } else if (EPI == 2) {
                    v += bias[n];
                    v = 0.5f * v * (1.0f + erff(v * 0.70710678118654752f));
                    ((u16*)outp)[idx] = f2bf(v);
                } else {
                    ((float*)outp)[idx] = v + bias[n] + bf2f(res_bf[idx]);
                }
            }
        }
    }
}

// ---------------------------------------------------------------------------
// Fused attention per (window, head): S = QK^T + 0.1*rpe ; Mpart = sum|S| ;
// P' = 1 - cos(S/||S||row * pi/2) ; O' = P' @ V  (M factor applied later).
// ---------------------------------------------------------------------------
__global__ __launch_bounds__(256) void attn_k(const u16* __restrict__ qkv,
                                              const float* __restrict__ rpe,
                                              float* __restrict__ Mpart,
                                              u16* __restrict__ Obuf) {
    const int blk = blockIdx.x;
    const int wh = blk >> 3, head = blk & 7;
    const int himg = wh & 63;
    const int t = threadIdx.x, l = t & 63, w = t >> 6;
    __shared__ __bf16 Qs[4096];
    __shared__ __bf16 Ks[4096];
    __shared__ __bf16 Vt[4096];
    __shared__ __bf16 Ps[4096];
    __shared__ float red[4];

    #pragma unroll
    for (int p = 0; p < 2; ++p) {
        const int sb = (p * 256 + t) << 4;
        const int row = sb >> 7;
        const int gl = ((sb >> 4) & 7) ^ (row & 7);
        const size_t gsrc = (size_t)(wh * 64 + row) * 1536 + head * 64 + gl * 8;
        const int lbase = p * 2048 + w * 512;
        load_lds16(qkv + gsrc, &Qs[lbase]);
        load_lds16(qkv + gsrc + 512, &Ks[lbase]);
    }
    {
        const int k = t >> 2, dc = (t & 3) * 16;
        const u16* vr = qkv + (size_t)(wh * 64 + k) * 1536 + 1024 + head * 64 + dc;
        u16x8 v0 = *(const u16x8*)vr;
        u16x8 v1 = *(const u16x8*)(vr + 8);
        const int g = k >> 3, klo = k & 7;
        #pragma unroll
        for (int i = 0; i < 8; ++i) {
            const int d0 = dc + i, d1 = dc + 8 + i;
            Vt[d0 * 64 + ((g ^ (d0 & 7)) << 3) + klo] = __builtin_bit_cast(__bf16, (u16)v0[i]);
            Vt[d1 * 64 + ((g ^ (d1 & 7)) << 3) + klo] = __builtin_bit_cast(__bf16, (u16)v1[i]);
        }
    }
    __syncthreads();

    const int r = l & 15, g4 = l >> 4;
    f32x4 acc[4] = {};
    #pragma unroll
    for (int h = 0; h < 2; ++h) {
        const int rowq = w * 16 + r;
        bf16x8 aq = *(const bf16x8*)&Qs[rowq * 64 + (((h * 4 + g4) ^ (rowq & 7)) << 3)];
        #pragma unroll
        for (int j = 0; j < 4; ++j) {
            const int rowk = j * 16 + r;
            bf16x8 bk = *(const bf16x8*)&Ks[rowk * 64 + (((h * 4 + g4) ^ (rowk & 7)) << 3)];
            acc[j] = __builtin_amdgcn_mfma_f32_16x16x32_bf16(aq, bk, acc[j], 0, 0, 0);
        }
    }

    float v[4][4];
    float asum = 0.f;
    float ss[4] = {0.f, 0.f, 0.f, 0.f};
    const size_t rpe_base = (size_t)(himg * 8 + head) * 4096 + (size_t)(w * 16 + g4 * 4) * 64 + r;
    #pragma unroll
    for (int j = 0; j < 4; ++j) {
        #pragma unroll
        for (int rr = 0; rr < 4; ++rr) {
            const float val = acc[j][rr] + 0.1f * rpe[rpe_base + rr * 64 + j * 16];
            v[j][rr] = val;
            asum += fabsf(val);
            ss[rr] += val * val;
        }
    }
    #pragma unroll
    for (int m = 1; m < 16; m <<= 1) {
        #pragma unroll
        for (int rr = 0; rr < 4; ++rr) ss[rr] += __shfl_xor(ss[rr], m);
    }
    float srev[4];
    #pragma unroll
    for (int rr = 0; rr < 4; ++rr)
        srev[rr] = 0.25f / fmaxf(sqrtf(ss[rr]), 1e-12f);

    #pragma unroll
    for (int j = 0; j < 4; ++j) {
        #pragma unroll
        for (int rr = 0; rr < 4; ++rr) {
            const float pv = 1.0f - __builtin_amdgcn_cosf(v[j][rr] * srev[rr]);
            const int rl = g4 * 4 + rr;
            const int c = j * 16 + r;
            Ps[w * 1024 + rl * 64 + (((c >> 3) ^ (rl & 7)) << 3) + (c & 7)] = f2bfr(pv);
        }
    }

    f32x4 oacc[4] = {};
    #pragma unroll
    for (int ks = 0; ks < 2; ++ks) {
        const int ga = ks * 4 + g4;
        bf16x8 pa = *(const bf16x8*)&Ps[w * 1024 + r * 64 + ((ga ^ (r & 7)) << 3)];
        #pragma unroll
        for (int j = 0; j < 4; ++j) {
            const int d = j * 16 + r;
            bf16x8 vb = *(const bf16x8*)&Vt[d * 64 + ((ga ^ (d & 7)) << 3)];
            oacc[j] = __builtin_amdgcn_mfma_f32_16x16x32_bf16(pa, vb, oacc[j], 0, 0, 0);
        }
    }

    #pragma unroll
    for (int j = 0; j < 4; ++j) {
        #pragma unroll
        for (int rr = 0; rr < 4; ++rr) {
            const int token = wh * 64 + w * 16 + g4 * 4 + rr;
            Obuf[(size_t)token * 512 + head * 64 + j * 16 + r] = f2bf(oacc[j][rr]);
        }
    }

    #pragma unroll
    for (int o = 1; o < 64; o <<= 1) asum += __shfl_xor(asum, o);
    if (l == 0) red[w] = asum;
    __syncthreads();
    if (t == 0) Mpart[blk] = red[0] + red[1] + red[2] + red[3];
}

// ---------------------------------------------------------------------------
// M finalize: M_w = mean|S| per window; M = max(M_w / max_w, 0.5). 1 block.
// ---------------------------------------------------------------------------
__global__ __launch_bounds__(256) void mfinal_k(const float* __restrict__ Mpart,
                                                float* __restrict__ M) {
    const int t = threadIdx.x;
    float m = 0.f;
    #pragma unroll
    for (int h = 0; h < 8; ++h) m += Mpart[t * 8 + h];
    m *= (1.0f / 32768.0f);
    float mx = m;
    #pragma unroll
    for (int o = 1; o < 64; o <<= 1) mx = fmaxf(mx, __shfl_xor(mx, o));
    __shared__ float red[4];
    if ((t & 63) == 0) red[t >> 6] = mx;
    __syncthreads();
    mx = fmaxf(fmaxf(red[0], red[1]), fmaxf(red[2], red[3]));
    M[t] = fmaxf(m / mx, 0.5f);
}

// ---------------------------------------------------------------------------
extern "C" void kernel_launch(void* const* d_in, const int* in_sizes, int n_in,
                              void* d_out, int out_size, void* d_ws, size_t ws_size,
                              hipStream_t stream) {
    (void)in_sizes; (void)n_in; (void)out_size; (void)ws_size;
    const float* x      = (const float*)d_in[0];
    const float* rpe    = (const float*)d_in[1];
    const float* qkv_w  = (const float*)d_in[2];
    const float* proj_w = (const float*)d_in[3];
    const float* proj_b = (const float*)d_in[4];
    const float* n1w    = (const float*)d_in[5];
    const float* n1b    = (const float*)d_in[6];
    const float* n2w    = (const float*)d_in[7];
    const float* n2b    = (const float*)d_in[8];
    const float* fc1w   = (const float*)d_in[9];
    const float* fc1b   = (const float*)d_in[10];
    const float* fc2w   = (const float*)d_in[11];
    const float* fc2b   = (const float*)d_in[12];
    float* out = (float*)d_out;

    char* ws = (char*)d_ws;
    float* Mpart = (float*)ws;                         // 8 KB
    float* Mbuf  = (float*)(ws + 8192);                // 1 KB
    u16* wqkv  = (u16*)(ws + 16384);                   // 1,572,864 B
    u16* wproj = (u16*)(ws + 16384 + 1572864);         // 524,288 B
    u16* wfc1  = (u16*)(ws + 16384 + 2097152);         // 2,097,152 B
    u16* wfc2  = (u16*)(ws + 16384 + 4194304);         // 2,097,152 B
    u16* bufA  = (u16*)(ws + 6307840);                 // 16.78 MB: img, then x1 (bf16)
    u16* bufB  = (u16*)(ws + 23085056);                // 16.78 MB: h1
    char* R    = ws + 39862272;                        // overlay region (67.1 MB)
    u16*   qkvb = (u16*)R;                             // 50,331,648 B
    u16*   Obuf = (u16*)(R + 50331648);                // 16,777,216 B
    u16*   gbuf = (u16*)R;                             // 67,108,864 B (qkv+O dead)

    // 0. all weight conversions f32->bf16 (one launch)
    cvt_all_k<<<3072, 256, 0, stream>>>(qkv_w, proj_w, fc1w, fc2w,
                                        wqkv, wproj, wfc1, wfc2);
    // 1. LN1: x -> img (bufA, bf16)
    ln_k<false><<<16384, 256, 0, stream>>>(x, n1w, n1b, bufA);
    // 2. qkv = img @ qkv_w^T  (qkvb bf16)
    gemm_bt<0, false><<<dim3(128, 12), 256, 0, stream>>>(
        bufA, wqkv, nullptr, nullptr, nullptr, qkvb, 16384, 1536, 512,
        nullptr, nullptr, nullptr);
    // 3. fused attention: O' (no M factor) + Mpart
    attn_k<<<2048, 256, 0, stream>>>(qkvb, rpe, Mpart, Obuf);
    // 4. M finalize
    mfinal_k<<<1, 256, 0, stream>>>(Mpart, Mbuf);
    // 5. x1 = x + a1 @ proj_w^T + proj_b -> bufA (bf16); a1 fused in staging
    gemm_bt<1, true><<<dim3(128, 4), 256, 0, stream>>>(
        nullptr, wproj, proj_b, x, nullptr, bufA, 16384, 512, 512,
        Mbuf, Obuf, x);
    // 6. LN2: x1 (bf16) -> h1 (bufB bf16)
    ln_k<true><<<16384, 256, 0, stream>>>(bufA, n2w, n2b, bufB);
    // 7. g = gelu(h1 @ fc1_w^T + fc1_b)  (gbuf bf16)
    gemm_bt<2, false><<<dim3(128, 16), 256, 0, stream>>>(
        bufB, wfc1, fc1b, nullptr, nullptr, gbuf, 16384, 2048, 512,
        nullptr, nullptr, nullptr);
    // 8. out = x1 + g @ fc2_w^T + fc2_b  (f32)
    gemm_bt<3, false><<<dim3(128, 4), 256, 0, stream>>>(
        gbuf, wfc2, fc2b, nullptr, bufA, out, 16384, 512, 2048,
        nullptr, nullptr, nullptr);
}

// Round 8
// 198.334 us; speedup vs baseline: 1.1552x; 1.0460x over previous
//
#include <hip/hip_runtime.h>
#include <hip/hip_bf16.h>
#include <math.h>

typedef unsigned short u16;
typedef __bf16 bf16x8 __attribute__((ext_vector_type(8)));
typedef float f32x4 __attribute__((ext_vector_type(4)));
typedef unsigned short u16x8 __attribute__((ext_vector_type(8)));

typedef const __attribute__((address_space(1))) void* gas_ptr;
typedef __attribute__((address_space(3))) void* las_ptr;

__device__ __forceinline__ float bf2f(u16 u) {
    union { unsigned int i; float f; } x;
    x.i = ((unsigned int)u) << 16;
    return x.f;
}
__device__ __forceinline__ u16 f2bf(float f) {
    __hip_bfloat16 h = __float2bfloat16(f);
    return __builtin_bit_cast(u16, h);
}
__device__ __forceinline__ __bf16 f2bfr(float f) {
    __hip_bfloat16 h = __float2bfloat16(f);
    return __builtin_bit_cast(__bf16, h);
}
__device__ __forceinline__ void load_lds16(const void* g, void* l) {
    __builtin_amdgcn_global_load_lds((gas_ptr)g, (las_ptr)l, 16, 0, 0);
}
// GELU with exact-erf semantics via A&S 7.1.26 (|err_erf| <= 1.5e-7).
__device__ __forceinline__ float gelu_f(float v) {
    const float a = fabsf(v) * 0.70710678118654752f;
    const float tt = 1.0f / fmaf(0.3275911f, a, 1.0f);
    float poly = fmaf(tt, 1.061405429f, -1.453152027f);
    poly = fmaf(tt, poly, 1.421413741f);
    poly = fmaf(tt, poly, -0.284496736f);
    poly = fmaf(tt, poly, 0.254829592f);
    const float erfa = 1.0f - poly * tt * __expf(-a * a);
    const float erfv = copysignf(erfa, v);
    return 0.5f * v * (1.0f + erfv);
}

// ---------------------------------------------------------------------------
// All 4 weight conversions f32->bf16 in one launch. 1024 elems/block.
// ---------------------------------------------------------------------------
__global__ __launch_bounds__(256) void cvt_all_k(const float* __restrict__ qkv_w,
                                                 const float* __restrict__ proj_w,
                                                 const float* __restrict__ fc1w,
                                                 const float* __restrict__ fc2w,
                                                 u16* __restrict__ wqkv,
                                                 u16* __restrict__ wproj,
                                                 u16* __restrict__ wfc1,
                                                 u16* __restrict__ wfc2) {
    const int b = blockIdx.x;
    const float* src; u16* dst; int off;
    if (b < 768)       { src = qkv_w;  dst = wqkv;  off = b; }
    else if (b < 1024) { src = proj_w; dst = wproj; off = b - 768; }
    else if (b < 2048) { src = fc1w;   dst = wfc1;  off = b - 1024; }
    else               { src = fc2w;   dst = wfc2;  off = b - 2048; }
    const int i = off * 256 + threadIdx.x;
    const float4 v = ((const float4*)src)[i];
    ushort4 o;
    o.x = f2bf(v.x); o.y = f2bf(v.y); o.z = f2bf(v.z); o.w = f2bf(v.w);
    ((ushort4*)dst)[i] = o;
}

// ---------------------------------------------------------------------------
// LayerNorm: one block per row (C=512), 256 threads, 2 elems/thread.
// ---------------------------------------------------------------------------
template<bool BF16IN>
__global__ __launch_bounds__(256) void ln_k(const void* __restrict__ inp,
                                            const float* __restrict__ gw,
                                            const float* __restrict__ gb,
                                            u16* __restrict__ outp) {
    const int row = blockIdx.x, t = threadIdx.x;
    float v0, v1;
    if (BF16IN) {
        const u16* rp = (const u16*)inp + (size_t)row * 512;
        v0 = bf2f(rp[2 * t]); v1 = bf2f(rp[2 * t + 1]);
    } else {
        const float2 v = ((const float2*)((const float*)inp + (size_t)row * 512))[t];
        v0 = v.x; v1 = v.y;
    }
    float s = v0 + v1, q = v0 * v0 + v1 * v1;
    #pragma unroll
    for (int o = 1; o < 64; o <<= 1) {
        s += __shfl_xor(s, o);
        q += __shfl_xor(q, o);
    }
    __shared__ float rs[4], rq[4];
    const int w = t >> 6;
    if ((t & 63) == 0) { rs[w] = s; rq[w] = q; }
    __syncthreads();
    s = rs[0] + rs[1] + rs[2] + rs[3];
    q = rq[0] + rq[1] + rq[2] + rq[3];
    const float mean = s * (1.0f / 512.0f);
    const float var = q * (1.0f / 512.0f) - mean * mean;
    const float rstd = rsqrtf(var + 1e-5f);
    u16* op = outp + (size_t)row * 512;
    op[2 * t]     = f2bf((v0 - mean) * rstd * gw[2 * t]     + gb[2 * t]);
    op[2 * t + 1] = f2bf((v1 - mean) * rstd * gw[2 * t + 1] + gb[2 * t + 1]);
}

// ---------------------------------------------------------------------------
// GEMM C[m,n] = sum_k A[m,k]*W[n,k] (+epilogue). 128x128 tile, BK=64,
// 4 waves (2x2), each wave 64x64 via 4x4 mfma 16x16x32 (x2 K-halves).
// One barrier pair per 64-wide K-tile (half the drains of BK=32).
// LDS 64 KB total -> 2 blocks/CU. Rows are 8 granules (16B) wide; slot =
// granule ^ (row&7) on BOTH stage-source and frag-read (bank-conflict-free:
// 16-lane service group covers 32 banks once for r=0..7, 2-way r=8..15).
// AFUSE: A-tile computed on the fly as a1 = M*O' + (1-M)*x (reg-staged
//        ds_write into the same swizzled LDS slots); A ptr unused.
// EPI 0: out bf16 = acc                          (qkv)
// EPI 1: out bf16 = acc + bias + res_f32         (proj -> x1 bf16)
// EPI 2: out bf16 = gelu(acc + bias)             (fc1)
// EPI 3: out f32  = acc + bias + bf16(res_bf)    (fc2 -> final)
// ---------------------------------------------------------------------------
template<int EPI, bool AFUSE>
__global__ __launch_bounds__(256) void gemm_bt(const u16* __restrict__ A,
                                               const u16* __restrict__ W,
                                               const float* __restrict__ bias,
                                               const float* __restrict__ res_f,
                                               const u16* __restrict__ res_bf,
                                               void* __restrict__ outp,
                                               int M, int N, int K,
                                               const float* __restrict__ aM,
                                               const u16* __restrict__ aO,
                                               const float* __restrict__ aX) {
    __shared__ __bf16 As[2][128 * 64];
    __shared__ __bf16 Bs[2][128 * 64];
    const int t = threadIdx.x;
    const int l = t & 63;
    const int w = t >> 6;
    const int wm = w & 1, wn = w >> 1;
    const int bm = blockIdx.x * 128, bn = blockIdx.y * 128;
    const int r = l & 15, g4 = l >> 4;

    f32x4 acc[4][4] = {};

    // staging geometry: 1024 granules/tile; thread t handles granules
    // {t, t+256, t+512, t+768} -> rows rowS+32j, within-row slot t&7.
    const int rowS = t >> 3;
    const int cS = (t & 7) ^ (rowS & 7);        // data granule for this slot
    const size_t rstep = (size_t)32 * K;        // 32 rows
    const u16* wBase = W + (size_t)(bn + rowS) * K + cS * 8;
    const u16* aBase = AFUSE ? nullptr : (A + (size_t)(bm + rowS) * K + cS * 8);
    const size_t afBase = (size_t)(bm + rowS) * K + cS * 8;   // AFUSE index

    auto stage = [&](int buf, int kt) {
        #pragma unroll
        for (int j = 0; j < 4; ++j) {
            if (AFUSE) {
                const size_t gidx = afBase + j * rstep + kt;
                const float Mw = aM[(bm + rowS + j * 32) >> 6];
                const float rf = 1.0f - Mw;
                const u16x8 ov = *(const u16x8*)(aO + gidx);
                const float4 x0 = *(const float4*)(aX + gidx);
                const float4 x1 = *(const float4*)(aX + gidx + 4);
                bf16x8 val;
                val[0] = f2bfr(Mw * bf2f(ov[0]) + rf * x0.x);
                val[1] = f2bfr(Mw * bf2f(ov[1]) + rf * x0.y);
                val[2] = f2bfr(Mw * bf2f(ov[2]) + rf * x0.z);
                val[3] = f2bfr(Mw * bf2f(ov[3]) + rf * x0.w);
                val[4] = f2bfr(Mw * bf2f(ov[4]) + rf * x1.x);
                val[5] = f2bfr(Mw * bf2f(ov[5]) + rf * x1.y);
                val[6] = f2bfr(Mw * bf2f(ov[6]) + rf * x1.z);
                val[7] = f2bfr(Mw * bf2f(ov[7]) + rf * x1.w);
                *(bf16x8*)&As[buf][(j * 256 + t) * 8] = val;
            } else {
                load_lds16(aBase + j * rstep + kt, &As[buf][(j * 256 + t) * 8]);
            }
            load_lds16(wBase + j * rstep + kt, &Bs[buf][(j * 256 + t) * 8]);
        }
    };

    const int nk = K >> 6;
    stage(0, 0);
    __syncthreads();
    for (int s = 0; s < nk; ++s) {
        if (s + 1 < nk) stage((s + 1) & 1, (s + 1) << 6);
        const int buf = s & 1;
        bf16x8 af[4][2], bfr[4][2];
        #pragma unroll
        for (int i = 0; i < 4; ++i) {
            const int ra = wm * 64 + i * 16 + r;
            const int rb = wn * 64 + i * 16 + r;
            #pragma unroll
            for (int h = 0; h < 2; ++h) {
                af[i][h]  = *(const bf16x8*)&As[buf][ra * 64 + (((h * 4 + g4) ^ (ra & 7)) << 3)];
                bfr[i][h] = *(const bf16x8*)&Bs[buf][rb * 64 + (((h * 4 + g4) ^ (rb & 7)) << 3)];
            }
        }
        #pragma unroll
        for (int i = 0; i < 4; ++i)
            #pragma unroll
            for (int j = 0; j < 4; ++j)
                #pragma unroll
                for (int h = 0; h < 2; ++h)
                    acc[i][j] = __builtin_amdgcn_mfma_f32_16x16x32_bf16(
                        af[i][h], bfr[j][h], acc[i][j], 0, 0, 0);
        __syncthreads();
    }

    #pragma unroll
    for (int i = 0; i < 4; ++i) {
        #pragma unroll
        for (int j = 0; j < 4; ++j) {
            #pragma unroll
            for (int rr = 0; rr < 4; ++rr) {
                const int m = bm + wm * 64 + i * 16 + g4 * 4 + rr;
                const int n = bn + wn * 64 + j * 16 + r;
                float v = acc[i][j][rr];
                const size_t idx = (size_t)m * N + n;
                if (EPI == 0) {
                    ((u16*)outp)[idx] = f2bf(v);
                } else if (EPI == 1) {
                    ((u16*)outp)[idx] = f2bf(v + bias[n] + res_f[idx]);
                } else if (EPI == 2) {
                    ((u16*)outp)[idx] = f2bf(gelu_f(v + bias[n]));
                } else {
                    ((float*)outp)[idx] = v + bias[n] + bf2f(res_bf[idx]);
                }
            }
        }
    }
}

// ---------------------------------------------------------------------------
// Fused attention per (window, head): S = QK^T + 0.1*rpe ; Mpart = sum|S| ;
// P' = 1 - cos(S/||S||row * pi/2) ; O' = P' @ V  (M factor applied later).
// ---------------------------------------------------------------------------
__global__ __launch_bounds__(256) void attn_k(const u16* __restrict__ qkv,
                                              const float* __restrict__ rpe,
                                              float* __restrict__ Mpart,
                                              u16* __restrict__ Obuf) {
    const int blk = blockIdx.x;
    const int wh = blk >> 3, head = blk & 7;
    const int himg = wh & 63;
    const int t = threadIdx.x, l = t & 63, w = t >> 6;
    __shared__ __bf16 Qs[4096];
    __shared__ __bf16 Ks[4096];
    __shared__ __bf16 Vt[4096];
    __shared__ __bf16 Ps[4096];
    __shared__ float red[4];

    #pragma unroll
    for (int p = 0; p < 2; ++p) {
        const int sb = (p * 256 + t) << 4;
        const int row = sb >> 7;
        const int gl = ((sb >> 4) & 7) ^ (row & 7);
        const size_t gsrc = (size_t)(wh * 64 + row) * 1536 + head * 64 + gl * 8;
        const int lbase = p * 2048 + w * 512;
        load_lds16(qkv + gsrc, &Qs[lbase]);
        load_lds16(qkv + gsrc + 512, &Ks[lbase]);
    }
    {
        const int k = t >> 2, dc = (t & 3) * 16;
        const u16* vr = qkv + (size_t)(wh * 64 + k) * 1536 + 1024 + head * 64 + dc;
        u16x8 v0 = *(const u16x8*)vr;
        u16x8 v1 = *(const u16x8*)(vr + 8);
        const int g = k >> 3, klo = k & 7;
        #pragma unroll
        for (int i = 0; i < 8; ++i) {
            const int d0 = dc + i, d1 = dc + 8 + i;
            Vt[d0 * 64 + ((g ^ (d0 & 7)) << 3) + klo] = __builtin_bit_cast(__bf16, (u16)v0[i]);
            Vt[d1 * 64 + ((g ^ (d1 & 7)) << 3) + klo] = __builtin_bit_cast(__bf16, (u16)v1[i]);
        }
    }
    __syncthreads();

    const int r = l & 15, g4 = l >> 4;
    f32x4 acc[4] = {};
    #pragma unroll
    for (int h = 0; h < 2; ++h) {
        const int rowq = w * 16 + r;
        bf16x8 aq = *(const bf16x8*)&Qs[rowq * 64 + (((h * 4 + g4) ^ (rowq & 7)) << 3)];
        #pragma unroll
        for (int j = 0; j < 4; ++j) {
            const int rowk = j * 16 + r;
            bf16x8 bk = *(const bf16x8*)&Ks[rowk * 64 + (((h * 4 + g4) ^ (rowk & 7)) << 3)];
            acc[j] = __builtin_amdgcn_mfma_f32_16x16x32_bf16(aq, bk, acc[j], 0, 0, 0);
        }
    }

    float v[4][4];
    float asum = 0.f;
    float ss[4] = {0.f, 0.f, 0.f, 0.f};
    const size_t rpe_base = (size_t)(himg * 8 + head) * 4096 + (size_t)(w * 16 + g4 * 4) * 64 + r;
    #pragma unroll
    for (int j = 0; j < 4; ++j) {
        #pragma unroll
        for (int rr = 0; rr < 4; ++rr) {
            const float val = acc[j][rr] + 0.1f * rpe[rpe_base + rr * 64 + j * 16];
            v[j][rr] = val;
            asum += fabsf(val);
            ss[rr] += val * val;
        }
    }
    #pragma unroll
    for (int m = 1; m < 16; m <<= 1) {
        #pragma unroll
        for (int rr = 0; rr < 4; ++rr) ss[rr] += __shfl_xor(ss[rr], m);
    }
    float srev[4];
    #pragma unroll
    for (int rr = 0; rr < 4; ++rr)
        srev[rr] = 0.25f / fmaxf(sqrtf(ss[rr]), 1e-12f);

    #pragma unroll
    for (int j = 0; j < 4; ++j) {
        #pragma unroll
        for (int rr = 0; rr < 4; ++rr) {
            const float pv = 1.0f - __builtin_amdgcn_cosf(v[j][rr] * srev[rr]);
            const int rl = g4 * 4 + rr;
            const int c = j * 16 + r;
            Ps[w * 1024 + rl * 64 + (((c >> 3) ^ (rl & 7)) << 3) + (c & 7)] = f2bfr(pv);
        }
    }

    f32x4 oacc[4] = {};
    #pragma unroll
    for (int ks = 0; ks < 2; ++ks) {
        const int ga = ks * 4 + g4;
        bf16x8 pa = *(const bf16x8*)&Ps[w * 1024 + r * 64 + ((ga ^ (r & 7)) << 3)];
        #pragma unroll
        for (int j = 0; j < 4; ++j) {
            const int d = j * 16 + r;
            bf16x8 vb = *(const bf16x8*)&Vt[d * 64 + ((ga ^ (d & 7)) << 3)];
            oacc[j] = __builtin_amdgcn_mfma_f32_16x16x32_bf16(pa, vb, oacc[j], 0, 0, 0);
        }
    }

    #pragma unroll
    for (int j = 0; j < 4; ++j) {
        #pragma unroll
        for (int rr = 0; rr < 4; ++rr) {
            const int token = wh * 64 + w * 16 + g4 * 4 + rr;
            Obuf[(size_t)token * 512 + head * 64 + j * 16 + r] = f2bf(oacc[j][rr]);
        }
    }

    #pragma unroll
    for (int o = 1; o < 64; o <<= 1) asum += __shfl_xor(asum, o);
    if (l == 0) red[w] = asum;
    __syncthreads();
    if (t == 0) Mpart[blk] = red[0] + red[1] + red[2] + red[3];
}

// ---------------------------------------------------------------------------
// M finalize: M_w = mean|S| per window; M = max(M_w / max_w, 0.5). 1 block.
// ---------------------------------------------------------------------------
__global__ __launch_bounds__(256) void mfinal_k(const float* __restrict__ Mpart,
                                                float* __restrict__ M) {
    const int t = threadIdx.x;
    float m = 0.f;
    #pragma unroll
    for (int h = 0; h < 8; ++h) m += Mpart[t * 8 + h];
    m *= (1.0f / 32768.0f);
    float mx = m;
    #pragma unroll
    for (int o = 1; o < 64; o <<= 1) mx = fmaxf(mx, __shfl_xor(mx, o));
    __shared__ float red[4];
    if ((t & 63) == 0) red[t >> 6] = mx;
    __syncthreads();
    mx = fmaxf(fmaxf(red[0], red[1]), fmaxf(red[2], red[3]));
    M[t] = fmaxf(m / mx, 0.5f);
}

// ---------------------------------------------------------------------------
extern "C" void kernel_launch(void* const* d_in, const int* in_sizes, int n_in,
                              void* d_out, int out_size, void* d_ws, size_t ws_size,
                              hipStream_t stream) {
    (void)in_sizes; (void)n_in; (void)out_size; (void)ws_size;
    const float* x      = (const float*)d_in[0];
    const float* rpe    = (const float*)d_in[1];
    const float* qkv_w  = (const float*)d_in[2];
    const float* proj_w = (const float*)d_in[3];
    const float* proj_b = (const float*)d_in[4];
    const float* n1w    = (const float*)d_in[5];
    const float* n1b    = (const float*)d_in[6];
    const float* n2w    = (const float*)d_in[7];
    const float* n2b    = (const float*)d_in[8];
    const float* fc1w   = (const float*)d_in[9];
    const float* fc1b   = (const float*)d_in[10];
    const float* fc2w   = (const float*)d_in[11];
    const float* fc2b   = (const float*)d_in[12];
    float* out = (float*)d_out;

    char* ws = (char*)d_ws;
    float* Mpart = (float*)ws;                         // 8 KB
    float* Mbuf  = (float*)(ws + 8192);                // 1 KB
    u16* wqkv  = (u16*)(ws + 16384);                   // 1,572,864 B
    u16* wproj = (u16*)(ws + 16384 + 1572864);         // 524,288 B
    u16* wfc1  = (u16*)(ws + 16384 + 2097152);         // 2,097,152 B
    u16* wfc2  = (u16*)(ws + 16384 + 4194304);         // 2,097,152 B
    u16* bufA  = (u16*)(ws + 6307840);                 // 16.78 MB: img, then x1 (bf16)
    u16* bufB  = (u16*)(ws + 23085056);                // 16.78 MB: h1
    char* R    = ws + 39862272;                        // overlay region (67.1 MB)
    u16*   qkvb = (u16*)R;                             // 50,331,648 B
    u16*   Obuf = (u16*)(R + 50331648);                // 16,777,216 B
    u16*   gbuf = (u16*)R;                             // 67,108,864 B (qkv+O dead)

    // 0. all weight conversions f32->bf16 (one launch)
    cvt_all_k<<<3072, 256, 0, stream>>>(qkv_w, proj_w, fc1w, fc2w,
                                        wqkv, wproj, wfc1, wfc2);
    // 1. LN1: x -> img (bufA, bf16)
    ln_k<false><<<16384, 256, 0, stream>>>(x, n1w, n1b, bufA);
    // 2. qkv = img @ qkv_w^T  (qkvb bf16)
    gemm_bt<0, false><<<dim3(128, 12), 256, 0, stream>>>(
        bufA, wqkv, nullptr, nullptr, nullptr, qkvb, 16384, 1536, 512,
        nullptr, nullptr, nullptr);
    // 3. fused attention: O' (no M factor) + Mpart
    attn_k<<<2048, 256, 0, stream>>>(qkvb, rpe, Mpart, Obuf);
    // 4. M finalize
    mfinal_k<<<1, 256, 0, stream>>>(Mpart, Mbuf);
    // 5. x1 = x + a1 @ proj_w^T + proj_b -> bufA (bf16); a1 fused in staging
    gemm_bt<1, true><<<dim3(128, 4), 256, 0, stream>>>(
        nullptr, wproj, proj_b, x, nullptr, bufA, 16384, 512, 512,
        Mbuf, Obuf, x);
    // 6. LN2: x1 (bf16) -> h1 (bufB bf16)
    ln_k<true><<<16384, 256, 0, stream>>>(bufA, n2w, n2b, bufB);
    // 7. g = gelu(h1 @ fc1_w^T + fc1_b)  (gbuf bf16)
    gemm_bt<2, false><<<dim3(128, 16), 256, 0, stream>>>(
        bufB, wfc1, fc1b, nullptr, nullptr, gbuf, 16384, 2048, 512,
        nullptr, nullptr, nullptr);
    // 8. out = x1 + g @ fc2_w^T + fc2_b  (f32)
    gemm_bt<3, false><<<dim3(128, 4), 256, 0, stream>>>(
        gbuf, wfc2, fc2b, nullptr, bufA, out, 16384, 512, 2048,
        nullptr, nullptr, nullptr);
}